// Round 15
// baseline (206.638 us; speedup 1.0000x reference)
//
#include <hip/hip_runtime.h>
#include <math.h>

// LocalityAttention, fp16 single-pass MFMA.
// Algebra: softmax(Q K^T) = softmax(q G k^T + colterm), G = Wq^T Wk;
// KG = k G^T replaces the K projection; Q projection eliminated.
// Round 15: row_prep and softmax_rows go 2-rows-per-wave (double in-flight
// bytes on the latency-bound streaming passes; 6 KB contiguous per wave).

typedef _Float16 f16x8 __attribute__((ext_vector_type(8)));
typedef _Float16 f16x4 __attribute__((ext_vector_type(4)));
typedef float f32x4 __attribute__((ext_vector_type(4)));

template<typename T>
__device__ __forceinline__ void async_copy16(T* lds, const T* g) {
    __builtin_amdgcn_global_load_lds(
        (const __attribute__((address_space(1))) unsigned int*)g,
        (__attribute__((address_space(3))) unsigned int*)lds, 16, 0, 0);
}

__device__ __forceinline__ void barrier_mem() {
    asm volatile("s_barrier" ::: "memory");
}

// ---------------- 256x256 8-phase GEMM: C[m,n] = sum_k A[m,k]*B[n,k] -----
// EPI: 0 fp32->C0; 1 fp16->C0; 2 fp32 scores: ((acc+cterm[bz*1024+col])/temp,
//      diag -> -inf).  BIAS: 0 none; 1 bias[col]; 2 bias[row].
template<int EPI, int BIAS>
__global__ __launch_bounds__(512, 2)
void mfma_gemm256(const _Float16* __restrict__ A, const _Float16* __restrict__ B,
                  const float* __restrict__ bias, void* __restrict__ C0,
                  int K, int lda, int ldb, int ldc,
                  long long sA, long long sB, long long sC,
                  const float* __restrict__ tptr, const float* __restrict__ cterm)
{
    __shared__ _Float16 smem[65536];   // 128 KiB: [buf][op][256*64]

    const int tid = threadIdx.x;

    const int gx = gridDim.x, gy = gridDim.y;
    const int nwg = gx * gy * gridDim.z;
    const int p = blockIdx.x + gx * (blockIdx.y + gy * blockIdx.z);
    const int cpx = nwg >> 3;
    const int l = (nwg & 7) ? p : (p & 7) * cpx + (p >> 3);
    const int bx = l % gx;
    const int by = (l / gx) % gy;
    const long long bz = l / (gx * gy);
    const int m0 = by * 256, n0 = bx * 256;

    const _Float16* A0 = A + bz * sA;
    const _Float16* B0 = B + bz * sB;

    const int lane = tid & 63;
    const int wid  = tid >> 6;
    const int wm   = wid >> 2;        // 0..1: A half (128 rows)
    const int wn   = wid & 3;         // 0..3: B quarter (64 rows)
    const int fr   = lane & 15;
    const int fs   = lane >> 4;

    const int nt = K / 64;
    const int iters = nt / 2;

    auto stage_unit = [&](int dbuf, int isB, int unit, int tile) {
        if (tile >= nt) return;
        const int kt = tile * 64;
        const int lr = tid >> 3, s = tid & 7;
        const int grow = isB ? (unit * 64 + lr)
                             : (((lr >> 5) << 7) + unit * 32 + (lr & 31));
        const int gslot = s ^ (grow & 7);
        _Float16* dst = smem + dbuf * 32768 + isB * 16384 + grow * 64 + s * 8;
        const _Float16* src = (isB ? B0 : A0)
            + (size_t)((isB ? n0 : m0) + grow) * (size_t)(isB ? ldb : lda)
            + kt + gslot * 8;
        async_copy16(dst, src);
    };

    f32x4 acc[8][4] = {};
    f16x8 bf[4][2];

#define PHASE(BUF, Q, READB, STAGES, VMW) do {                                 \
    const _Float16* Ab = smem + (BUF) * 32768;                                 \
    const _Float16* Bb = Ab + 16384;                                           \
    f16x8 a0k0, a0k1, a1k0, a1k1;                                              \
    { const int r = wm * 128 + ((Q) * 2 + 0) * 16 + fr;                        \
      a0k0 = *(const f16x8*)&Ab[r * 64 + ((fs       ^ (r & 7)) * 8)];          \
      a0k1 = *(const f16x8*)&Ab[r * 64 + (((4 + fs) ^ (r & 7)) * 8)]; }        \
    { const int r = wm * 128 + ((Q) * 2 + 1) * 16 + fr;                        \
      a1k0 = *(const f16x8*)&Ab[r * 64 + ((fs       ^ (r & 7)) * 8)];          \
      a1k1 = *(const f16x8*)&Ab[r * 64 + (((4 + fs) ^ (r & 7)) * 8)]; }        \
    if (READB) {                                                               \
      _Pragma("unroll") for (int ni = 0; ni < 4; ++ni) {                       \
        const int r = wn * 64 + ni * 16 + fr;                                  \
        bf[ni][0] = *(const f16x8*)&Bb[r * 64 + ((fs       ^ (r & 7)) * 8)];   \
        bf[ni][1] = *(const f16x8*)&Bb[r * 64 + (((4 + fs) ^ (r & 7)) * 8)]; } \
    }                                                                          \
    STAGES;                                                                    \
    barrier_mem();                                                             \
    __builtin_amdgcn_s_setprio(1);                                             \
    _Pragma("unroll") for (int ni = 0; ni < 4; ++ni) {                         \
      acc[(Q)*2+0][ni] = __builtin_amdgcn_mfma_f32_16x16x32_f16(a0k0, bf[ni][0], acc[(Q)*2+0][ni], 0, 0, 0); \
      acc[(Q)*2+0][ni] = __builtin_amdgcn_mfma_f32_16x16x32_f16(a0k1, bf[ni][1], acc[(Q)*2+0][ni], 0, 0, 0); \
      acc[(Q)*2+1][ni] = __builtin_amdgcn_mfma_f32_16x16x32_f16(a1k0, bf[ni][0], acc[(Q)*2+1][ni], 0, 0, 0); \
      acc[(Q)*2+1][ni] = __builtin_amdgcn_mfma_f32_16x16x32_f16(a1k1, bf[ni][1], acc[(Q)*2+1][ni], 0, 0, 0); \
    }                                                                          \
    __builtin_amdgcn_s_setprio(0);                                             \
    VMW;                                                                       \
    barrier_mem();                                                             \
} while (0)

    stage_unit(0, 0, 0, 0); stage_unit(0, 0, 1, 0);
    stage_unit(0, 0, 2, 0); stage_unit(0, 0, 3, 0);
    stage_unit(0, 1, 0, 0); stage_unit(0, 1, 1, 0);
    stage_unit(0, 1, 2, 0); stage_unit(0, 1, 3, 0);
    stage_unit(1, 1, 0, 1); stage_unit(1, 1, 1, 1);
    stage_unit(1, 1, 2, 1); stage_unit(1, 1, 3, 1);
    stage_unit(1, 0, 0, 1); stage_unit(1, 0, 1, 1);
    asm volatile("s_waitcnt vmcnt(6)" ::: "memory");
    barrier_mem();

    for (int i = 0; i < iters; ++i) {
        const int T1 = 2 * i + 1, T2 = 2 * i + 2, T3 = 2 * i + 3;
        const bool last = (i + 1 == iters);
        PHASE(0, 0, 1, stage_unit(1, 0, 2, T1); stage_unit(1, 0, 3, T1), );
        PHASE(0, 1, 0, stage_unit(0, 1, 0, T2); stage_unit(0, 1, 1, T2), );
        PHASE(0, 2, 0, stage_unit(0, 1, 2, T2); stage_unit(0, 1, 3, T2), );
        PHASE(0, 3, 0, stage_unit(0, 0, 0, T2); stage_unit(0, 0, 1, T2),
              if (last) { asm volatile("s_waitcnt vmcnt(0)" ::: "memory"); }
              else      { asm volatile("s_waitcnt vmcnt(6)" ::: "memory"); });
        PHASE(1, 0, 1, stage_unit(0, 0, 2, T2); stage_unit(0, 0, 3, T2), );
        PHASE(1, 1, 0, stage_unit(1, 1, 0, T3); stage_unit(1, 1, 1, T3), );
        PHASE(1, 2, 0, stage_unit(1, 1, 2, T3); stage_unit(1, 1, 3, T3), );
        PHASE(1, 3, 0, stage_unit(1, 0, 0, T3); stage_unit(1, 0, 1, T3),
              asm volatile("s_waitcnt vmcnt(6)" ::: "memory"));
    }
#undef PHASE

    // epilogue constants for scores mode
    float invt = 0.f, ct[4];
    if (EPI == 2) {
        invt = 1.0f / tptr[0];
        #pragma unroll
        for (int ni = 0; ni < 4; ++ni)
            ct[ni] = cterm[bz * 1024 + n0 + wn * 64 + ni * 16 + fr];
    }

    #pragma unroll
    for (int mi = 0; mi < 8; ++mi) {
        #pragma unroll
        for (int ni = 0; ni < 4; ++ni) {
            const int col = n0 + wn * 64 + ni * 16 + fr;
            #pragma unroll
            for (int r = 0; r < 4; ++r) {
                const int row = m0 + wm * 128 + mi * 16 + fs * 4 + r;
                float vv = acc[mi][ni][r];
                if (BIAS == 1) vv += bias[col];
                if (BIAS == 2) vv += bias[row];
                const size_t idx = (size_t)bz * sC + (size_t)row * ldc + col;
                if (EPI == 0) {
                    ((float*)C0)[idx] = vv;
                } else if (EPI == 2) {
                    vv = (vv + ct[ni]) * invt;
                    if (row == col) vv = -INFINITY;
                    ((float*)C0)[idx] = vv;
                } else {
                    ((_Float16*)C0)[idx] = (_Float16)vv;
                }
            }
        }
    }
}

// ---------------- 128x128 2-phase GEMM (tiny G matmul) ----------------------
template<int EPI, int BIAS>
__global__ __launch_bounds__(256, 2)
void mfma_gemm(const _Float16* __restrict__ A, const _Float16* __restrict__ B,
               const float* __restrict__ bias,
               void* __restrict__ C0,
               int K, int lda, int ldb, int ldc,
               long long sA, long long sB, long long sC)
{
    __shared__ _Float16 sAh[128 * 32];
    __shared__ _Float16 sBh[128 * 32];

    const int tid = threadIdx.x;
    const int gx = gridDim.x, gy = gridDim.y;
    const int nwg = gx * gy * gridDim.z;
    const int p = blockIdx.x + gx * (blockIdx.y + gy * blockIdx.z);
    const int cpx = nwg >> 3;
    const int l = (nwg & 7) ? p : (p & 7) * cpx + (p >> 3);
    const int bx = l % gx;
    const int by = (l / gx) % gy;
    const long long bz = l / (gx * gy);

    const int m0 = by * 128;
    const int n0 = bx * 128;

    const _Float16* A0 = A + bz * sA;
    const _Float16* B0 = B + bz * sB;

    const int lrow  = tid >> 2;
    const int lslot = tid & 3;

    const int lane = tid & 63;
    const int wv   = tid >> 6;
    const int wm   = wv >> 1, wn = wv & 1;
    const int fr   = lane & 15;
    const int fs   = lane >> 4;
    const int sw   = fs ^ (fr & 3);
    const int abase = (wm * 64 + fr) * 32 + sw * 8;
    const int bbase = (wn * 64 + fr) * 32 + sw * 8;

    f32x4 acc[4][4] = {};

    for (int kt = 0; kt < K; kt += 32) {
        #pragma unroll
        for (int it = 0; it < 2; ++it) {
            const int row = lrow + it * 64;
            const int gsl = (lslot ^ (row & 3)) << 3;
            const size_t loff = (size_t)tid * 8 + (size_t)it * 2048;
            async_copy16(&sAh[loff], A0 + (size_t)(m0 + row) * lda + kt + gsl);
            async_copy16(&sBh[loff], B0 + (size_t)(n0 + row) * ldb + kt + gsl);
        }
        __syncthreads();

        f16x8 ah[4], bh[4];
        #pragma unroll
        for (int i = 0; i < 4; ++i) {
            ah[i] = *(const f16x8*)&sAh[abase + i * 512];
            bh[i] = *(const f16x8*)&sBh[bbase + i * 512];
        }
        #pragma unroll
        for (int mi = 0; mi < 4; ++mi)
            #pragma unroll
            for (int ni = 0; ni < 4; ++ni)
                acc[mi][ni] = __builtin_amdgcn_mfma_f32_16x16x32_f16(
                    ah[mi], bh[ni], acc[mi][ni], 0, 0, 0);
        __syncthreads();
    }

    const int er = fs * 4;
    #pragma unroll
    for (int mi = 0; mi < 4; ++mi) {
        #pragma unroll
        for (int ni = 0; ni < 4; ++ni) {
            const int col = n0 + wn * 64 + ni * 16 + fr;
            #pragma unroll
            for (int r = 0; r < 4; ++r) {
                const int row = m0 + wm * 64 + mi * 16 + er + r;
                float vv = acc[mi][ni][r];
                if (BIAS == 1) vv += bias[col];
                if (BIAS == 2) vv += bias[row];
                const size_t idx = (size_t)bz * sC + (size_t)row * ldc + col;
                if (EPI == 0) ((float*)C0)[idx] = vv;
                else          ((_Float16*)C0)[idx] = (_Float16)vv;
            }
        }
    }
}

// ---------------- weights prep: Wv convert + Wq/Wk transposes ---------------
__global__ __launch_bounds__(256)
void weights_prep(const float* __restrict__ Wq, const float* __restrict__ Wk,
                  const float* __restrict__ Wv,
                  _Float16* __restrict__ WqT, _Float16* __restrict__ WkT,
                  _Float16* __restrict__ wvh)
{
    __shared__ float t[64][65];
    const int p = blockIdx.x;
    const int tid = threadIdx.x;

    if (p < 288) {
        const long long i = ((long long)p * 256 + tid) * 8;
        const float4 a = *(const float4*)&Wv[i];
        const float4 b = *(const float4*)&Wv[i + 4];
        f16x8 o;
        o[0] = (_Float16)a.x; o[1] = (_Float16)a.y;
        o[2] = (_Float16)a.z; o[3] = (_Float16)a.w;
        o[4] = (_Float16)b.x; o[5] = (_Float16)b.y;
        o[6] = (_Float16)b.z; o[7] = (_Float16)b.w;
        *(f16x8*)&wvh[i] = o;
        return;
    }
    const int tno = p < 432 ? p - 288 : p - 432;
    const float* src = p < 432 ? Wq : Wk;
    _Float16* dst    = p < 432 ? WqT : WkT;
    const int r0 = (tno / 12) * 64, c0 = (tno % 12) * 64;
    const int tx = tid & 63, ty = tid >> 6;
    #pragma unroll
    for (int r = 0; r < 16; ++r) {
        const int row = ty * 16 + r;
        t[row][tx] = src[(size_t)(r0 + row) * 768 + c0 + tx];
    }
    __syncthreads();
    #pragma unroll
    for (int r = 0; r < 16; ++r) {
        const int orow = ty * 16 + r;
        dst[(size_t)(c0 + orow) * 768 + r0 + tx] = (_Float16)t[tx][orow];
    }
}

// colvec[d] = sum_e WkT[d][e]*bq[e]
__global__ __launch_bounds__(256)
void colvec_kernel(const _Float16* __restrict__ WkT, const float* __restrict__ bq,
                   float* __restrict__ colvec, int n)
{
    const int wv = threadIdx.x >> 6, lane = threadIdx.x & 63;
    const int d = blockIdx.x * 4 + wv;
    float s = 0.f;
    for (int e = lane; e < n; e += 64)
        s += (float)WkT[(size_t)d * n + e] * bq[e];
    #pragma unroll
    for (int off = 32; off; off >>= 1) s += __shfl_down(s, off, 64);
    if (lane == 0) colvec[d] = s;
}

// Unified row-pattern convert, 2 rows per wave (6 nt loads in flight, 6 KB
// contiguous per wave). 6144 blocks:
//  [0,2048)      k -> kh + cterm   (8 rows/block)
//  [2048,4096)   q -> qh
//  [4096,6144)   v -> vh
__global__ __launch_bounds__(256)
void row_prep(const float* __restrict__ k, const float* __restrict__ q,
              const float* __restrict__ v, const float* __restrict__ colvec,
              float* __restrict__ cterm, _Float16* __restrict__ kh,
              _Float16* __restrict__ qh, _Float16* __restrict__ vh)
{
    const int p = blockIdx.x;
    const int wv = threadIdx.x >> 6, lane = threadIdx.x & 63;

    if (p < 2048) {
        const long long r0 = (long long)p * 8 + wv * 2;
        const float* kp0 = k + r0 * 768;
        const float* kp1 = kp0 + 768;
        _Float16* op0 = kh + r0 * 768;
        _Float16* op1 = op0 + 768;
        f32x4 a0[3], a1[3];
        #pragma unroll
        for (int i = 0; i < 3; ++i)
            a0[i] = __builtin_nontemporal_load((const f32x4*)&kp0[lane * 4 + i * 256]);
        #pragma unroll
        for (int i = 0; i < 3; ++i)
            a1[i] = __builtin_nontemporal_load((const f32x4*)&kp1[lane * 4 + i * 256]);
        float s0 = 0.f, s1 = 0.f;
        #pragma unroll
        for (int i = 0; i < 3; ++i) {
            const float4 c = *(const float4*)&colvec[lane * 4 + i * 256];
            s0 += a0[i].x * c.x + a0[i].y * c.y + a0[i].z * c.z + a0[i].w * c.w;
            s1 += a1[i].x * c.x + a1[i].y * c.y + a1[i].z * c.z + a1[i].w * c.w;
            f16x4 o0, o1;
            o0[0] = (_Float16)a0[i].x; o0[1] = (_Float16)a0[i].y;
            o0[2] = (_Float16)a0[i].z; o0[3] = (_Float16)a0[i].w;
            o1[0] = (_Float16)a1[i].x; o1[1] = (_Float16)a1[i].y;
            o1[2] = (_Float16)a1[i].z; o1[3] = (_Float16)a1[i].w;
            *(f16x4*)&op0[lane * 4 + i * 256] = o0;
            *(f16x4*)&op1[lane * 4 + i * 256] = o1;
        }
        #pragma unroll
        for (int off = 32; off; off >>= 1) {
            s0 += __shfl_down(s0, off, 64);
            s1 += __shfl_down(s1, off, 64);
        }
        if (lane == 0) { cterm[r0] = s0; cterm[r0 + 1] = s1; }
        return;
    }
    const int pp = p < 4096 ? p - 2048 : p - 4096;
    const float* src = p < 4096 ? q : v;
    _Float16* dst    = p < 4096 ? qh : vh;
    const long long r0 = (long long)pp * 8 + wv * 2;
    const float* sp0 = src + r0 * 768;
    const float* sp1 = sp0 + 768;
    _Float16* op0 = dst + r0 * 768;
    _Float16* op1 = op0 + 768;
    f32x4 a0[3], a1[3];
    #pragma unroll
    for (int i = 0; i < 3; ++i)
        a0[i] = __builtin_nontemporal_load((const f32x4*)&sp0[lane * 4 + i * 256]);
    #pragma unroll
    for (int i = 0; i < 3; ++i)
        a1[i] = __builtin_nontemporal_load((const f32x4*)&sp1[lane * 4 + i * 256]);
    #pragma unroll
    for (int i = 0; i < 3; ++i) {
        f16x4 o0, o1;
        o0[0] = (_Float16)a0[i].x; o0[1] = (_Float16)a0[i].y;
        o0[2] = (_Float16)a0[i].z; o0[3] = (_Float16)a0[i].w;
        o1[0] = (_Float16)a1[i].x; o1[1] = (_Float16)a1[i].y;
        o1[2] = (_Float16)a1[i].z; o1[3] = (_Float16)a1[i].w;
        *(f16x4*)&op0[lane * 4 + i * 256] = o0;
        *(f16x4*)&op1[lane * 4 + i * 256] = o1;
    }
}

// Pure row softmax, 2 rows per wave (mask/cterm/temp already applied by the
// scores epilogue). 2048 blocks, XCD-matched to the scores GEMM chunk map.
__global__ __launch_bounds__(256)
void softmax_rows(const float* __restrict__ P, _Float16* __restrict__ Pout)
{
    const int p = blockIdx.x;                       // 2048 blocks
    const int wv = threadIdx.x >> 6, lane = threadIdx.x & 63;
    const int r0 = (p & 7) * 2048 + (p >> 3) * 8 + wv * 2;
    const float* rp0 = P + (long long)r0 * 1024;
    const float* rp1 = rp0 + 1024;

    float v0[16], v1[16];
    #pragma unroll
    for (int i = 0; i < 4; ++i) {
        const float4 a = *(const float4*)&rp0[lane * 4 + i * 256];
        v0[i * 4 + 0] = a.x; v0[i * 4 + 1] = a.y;
        v0[i * 4 + 2] = a.z; v0[i * 4 + 3] = a.w;
    }
    #pragma unroll
    for (int i = 0; i < 4; ++i) {
        const float4 a = *(const float4*)&rp1[lane * 4 + i * 256];
        v1[i * 4 + 0] = a.x; v1[i * 4 + 1] = a.y;
        v1[i * 4 + 2] = a.z; v1[i * 4 + 3] = a.w;
    }

    float m0 = v0[0], m1 = v1[0];
    #pragma unroll
    for (int j = 1; j < 16; ++j) { m0 = fmaxf(m0, v0[j]); m1 = fmaxf(m1, v1[j]); }
    #pragma unroll
    for (int off = 32; off; off >>= 1) {
        m0 = fmaxf(m0, __shfl_xor(m0, off, 64));
        m1 = fmaxf(m1, __shfl_xor(m1, off, 64));
    }

    float e0[16], e1[16], s0 = 0.f, s1 = 0.f;
    #pragma unroll
    for (int j = 0; j < 16; ++j) {
        e0[j] = expf(v0[j] - m0); s0 += e0[j];
        e1[j] = expf(v1[j] - m1); s1 += e1[j];
    }
    #pragma unroll
    for (int off = 32; off; off >>= 1) {
        s0 += __shfl_xor(s0, off, 64);
        s1 += __shfl_xor(s1, off, 64);
    }

    const float i0 = 1.0f / s0, i1 = 1.0f / s1;
    _Float16* op0 = Pout + (long long)r0 * 1024;
    _Float16* op1 = op0 + 1024;
    #pragma unroll
    for (int i = 0; i < 4; ++i) {
        f16x4 o;
        o[0] = (_Float16)(e0[i * 4 + 0] * i0);
        o[1] = (_Float16)(e0[i * 4 + 1] * i0);
        o[2] = (_Float16)(e0[i * 4 + 2] * i0);
        o[3] = (_Float16)(e0[i * 4 + 3] * i0);
        *(f16x4*)&op0[lane * 4 + i * 256] = o;
    }
    #pragma unroll
    for (int i = 0; i < 4; ++i) {
        f16x4 o;
        o[0] = (_Float16)(e1[i * 4 + 0] * i1);
        o[1] = (_Float16)(e1[i * 4 + 1] * i1);
        o[2] = (_Float16)(e1[i * 4 + 2] * i1);
        o[3] = (_Float16)(e1[i * 4 + 3] * i1);
        *(f16x4*)&op1[lane * 4 + i * 256] = o;
    }
}

extern "C" void kernel_launch(void* const* d_in, const int* in_sizes, int n_in,
                              void* d_out, int out_size, void* d_ws, size_t ws_size,
                              hipStream_t stream)
{
    const float* q    = (const float*)d_in[0];
    const float* k    = (const float*)d_in[1];
    const float* v    = (const float*)d_in[2];
    const float* Wq   = (const float*)d_in[3];
    const float* bq   = (const float*)d_in[4];
    const float* Wk   = (const float*)d_in[5];
    const float* bk   = (const float*)d_in[6];   // row-constant -> cancels in softmax
    const float* Wv   = (const float*)d_in[7];
    const float* bv   = (const float*)d_in[8];
    const float* temp = (const float*)d_in[9];
    (void)bk;

    const int S = 1024, D = 768;

    // ws layout (bytes), end 197,725,184 (ws is 256 MiB).
    // P (32 MB compact fp16) overlays qh+kh, both dead by softmax time.
    char* ws = (char*)d_ws;
    _Float16* qh  = (_Float16*)(ws + 0);          // 24 MB (dead after scores)
    _Float16* kh  = (_Float16*)(ws + 25165824);   // 24 MB (dead after KG)
    _Float16* Pc  = (_Float16*)(ws + 0);          // 32 MB compact P
    _Float16* vh  = (_Float16*)(ws + 50331648);   // 24 MB
    _Float16* VT  = (_Float16*)(ws + 75497472);   // 24 MB
    _Float16* KG  = (_Float16*)(ws + 100663296);  // 24 MB
    float*  scores = (float*)(ws + 125829120);    // 64 MiB
    _Float16* wvh = (_Float16*)(ws + 192937984);  // 1.125 MB
    _Float16* WqT = (_Float16*)(ws + 194117632);
    _Float16* WkT = (_Float16*)(ws + 195297280);
    _Float16* G   = (_Float16*)(ws + 196476928);
    float* colvec = (float*)(ws + 197656576);
    float* cterm  = (float*)(ws + 197659648);

    dim3 blk(256);
    dim3 blk512(512);

    // weight preps, then colvec (needs WkT), then unified k/q/v row convert
    weights_prep<<<576, blk, 0, stream>>>(Wq, Wk, Wv, WqT, WkT, wvh);
    colvec_kernel<<<192, blk, 0, stream>>>(WkT, bq, colvec, D);
    row_prep<<<6144, blk, 0, stream>>>(k, q, v, colvec, cterm, kh, qh, vh);

    // G[d,d'] = sum_e Wq[e,d] Wk[e,d']  (tiny, 128^2 path)
    mfma_gemm<1, 0><<<dim3(6, 6, 1), blk, 0, stream>>>(
        WqT, WkT, nullptr, G,
        768, 768, 768, 768, 0, 0, 0);

    // KG[j,d] = sum_d' k[j,d'] G[d,d']  (M=16384 flat, N=768, K=768)
    mfma_gemm256<1, 0><<<dim3(3, 64, 1), blk512, 0, stream>>>(
        kh, G, nullptr, KG,
        768, 768, 768, 768, 0, 0, 0, nullptr, nullptr);

    // VT[b][e][s] = sum_d Wv[e,d] v[b,s,d] + bv[e]  (M=768, N=1024, K=768)
    mfma_gemm256<1, 2><<<dim3(4, 3, 16), blk512, 0, stream>>>(
        wvh, vh, bv, VT,
        768, 768, 768, 1024, 0, (long long)S * D, (long long)D * S,
        nullptr, nullptr);

    // scores[b] = (q[b] (KG[b])^T + cterm)/temp, diag -> -inf  (EPI=2)
    mfma_gemm256<2, 0><<<dim3(4, 4, 16), blk512, 0, stream>>>(
        qh, KG, nullptr, scores,
        768, 768, 768, 1024,
        (long long)S * D, (long long)S * D, (long long)S * S,
        temp, cterm);

    // pure row softmax -> compact fp16 P (stride 1024)
    softmax_rows<<<2048, blk, 0, stream>>>(scores, Pc);

    // out[b] = P[b] VT[b]^T  (M=1024, N=768, K=1024; compact P, lda=1024)
    mfma_gemm256<0, 0><<<dim3(3, 4, 16), blk512, 0, stream>>>(
        Pc, VT, nullptr, d_out,
        1024, 1024, 1024, 768,
        (long long)S * S, (long long)D * S, (long long)S * D,
        nullptr, nullptr);
}